// Round 4
// baseline (956.580 us; speedup 1.0000x reference)
//
#include <hip/hip_runtime.h>
#include <math.h>

#define NTOK   16384
#define DDIM   1024
#define HDIM   128
#define NEXP   32
#define NROUTE 30
#define TOPK   4
#define TS     32
#define NJOBS  544          // 8*68

typedef short bf16x8 __attribute__((ext_vector_type(8)));
typedef float f32x16 __attribute__((ext_vector_type(16)));
typedef unsigned short u16;

__device__ __forceinline__ float sigmoidf_(float x) { return 1.f / (1.f + expf(-x)); }

__device__ __forceinline__ u16 f2bf(float x) {
  unsigned u = __float_as_uint(x);
  u += 0x7fffu + ((u >> 16) & 1u);
  return (u16)(u >> 16);
}
__device__ __forceinline__ float bf2f(u16 v) {
  return __uint_as_float(((unsigned)v) << 16);
}

__device__ __forceinline__ f32x16 mfma32(uint4 a, uint4 b, f32x16 c) {
  union { uint4 u; bf16x8 h; } A, B;
  A.u = a; B.u = b;
  return __builtin_amdgcn_mfma_f32_32x32x16_bf16(A.h, B.h, c, 0, 0, 0);
}

__device__ __forceinline__ void gload16(const void* g, void* l) {
  __builtin_amdgcn_global_load_lds(
      (const __attribute__((address_space(1))) unsigned int*)g,
      (__attribute__((address_space(3))) unsigned int*)l, 16, 0, 0);
}

// wait own vmem (incl. global_load_lds) then barrier — counted scheme kept
// simple/safe: vmcnt(0), but loads were issued a full chunk earlier.
__device__ __forceinline__ void wait_bar0() {
  asm volatile("s_waitcnt vmcnt(0)\ns_barrier" ::: "memory");
  __builtin_amdgcn_sched_barrier(0);
}
// lgkm-only barrier: LDS writes visible, vmem (prefetch) stays in flight.
__device__ __forceinline__ void lgkm_bar() {
  asm volatile("s_waitcnt lgkmcnt(0)\ns_barrier" ::: "memory");
  __builtin_amdgcn_sched_barrier(0);
}

// ---------------- prep: X fp32 -> bf16 ----------------
__global__ __launch_bounds__(256) void cvt_x_kernel(const float* __restrict__ X,
                                                    u16* __restrict__ Xb)
{
  const size_t base = ((size_t)blockIdx.x * 256 + threadIdx.x) * 16;
  u16 v[16];
#pragma unroll
  for (int i = 0; i < 4; ++i) {
    const float4 f = *(const float4*)(X + base + i * 4);
    v[i*4+0] = f2bf(f.x); v[i*4+1] = f2bf(f.y);
    v[i*4+2] = f2bf(f.z); v[i*4+3] = f2bf(f.w);
  }
  *(uint4*)(Xb + base) = *(const uint4*)v;
  *(uint4*)(Xb + base + 8) = *(const uint4*)(v + 8);
}

// ---- prep: keys [E][D][H] -> Kc[e][kc][r=h][perm-k] bf16, chunk-contiguous ----
__global__ __launch_bounds__(256) void prep_k_kernel(const float* __restrict__ K,
                                                     u16* __restrict__ Kc)
{
  __shared__ float t[128][129];
  const int kc = blockIdx.x, e = blockIdx.y, tid = threadIdx.x;
#pragma unroll
  for (int i = 0; i < 64; ++i) {
    const int g = tid + i * 256;
    const int d = g >> 7, h = g & 127;
    t[d][h] = K[((size_t)e * DDIM + kc * 128 + d) * HDIM + h];
  }
  __syncthreads();
  u16* dst = Kc + ((size_t)e * 8 + kc) * 16384;
#pragma unroll
  for (int i = 0; i < 64; ++i) {
    const int f = tid + i * 256;
    const int r = f >> 7, c = f & 127;
    const int k = (((c >> 3) ^ (r & 15)) << 3) | (c & 7);
    dst[f] = f2bf(t[k][r]);
  }
}

// ---- prep: values [E][H][D] -> Vc[e][dc][r=d][perm-h] bf16 ----
__global__ __launch_bounds__(256) void prep_v_kernel(const float* __restrict__ V,
                                                     u16* __restrict__ Vc)
{
  __shared__ float t[128][129];
  const int dc = blockIdx.x, e = blockIdx.y, tid = threadIdx.x;
#pragma unroll
  for (int i = 0; i < 64; ++i) {
    const int g = tid + i * 256;
    const int h = g >> 7, dl = g & 127;
    t[h][dl] = V[((size_t)e * HDIM + h) * DDIM + dc * 128 + dl];
  }
  __syncthreads();
  u16* dst = Vc + ((size_t)e * 8 + dc) * 16384;
#pragma unroll
  for (int i = 0; i < 64; ++i) {
    const int f = tid + i * 256;
    const int r = f >> 7, c = f & 127;
    const int h = (((c >> 3) ^ (r & 15)) << 3) | (c & 7);
    dst[f] = f2bf(t[h][r]);
  }
}

// ---------------- router: lane-local k-partition + LDS transpose reduce ----------------
__global__ __launch_bounds__(256) void router_kernel(
    const float* __restrict__ SI, const float* __restrict__ ES,
    const float* __restrict__ bias, float* __restrict__ out_sel,
    float* __restrict__ w6, int* __restrict__ sel_e, int* __restrict__ counts)
{
  __shared__ float pbuf[4][32][68];   // [wave][pair=(ei*4+t)][lane], padded
  __shared__ float aff[16][33];       // [token][expert]
  const int wave = threadIdx.x >> 6, lane = threadIdx.x & 63;
  const int tok0 = blockIdx.x * 16 + wave * 4;

  // lane owns k in [lane*16, lane*16+16)
  float x[4][16];
#pragma unroll
  for (int t = 0; t < 4; ++t) {
    const float* xp = SI + (size_t)(tok0 + t) * DDIM + lane * 16;
#pragma unroll
    for (int q = 0; q < 4; ++q) {
      const float4 v = *(const float4*)(xp + q * 4);
      x[t][q*4+0]=v.x; x[t][q*4+1]=v.y; x[t][q*4+2]=v.z; x[t][q*4+3]=v.w;
    }
  }

#pragma unroll
  for (int g = 0; g < 4; ++g) {
#pragma unroll
    for (int ei = 0; ei < 8; ++ei) {
      const int e = g * 8 + ei;
      float es[16];
      const float* ep = ES + (size_t)e * DDIM + lane * 16;
#pragma unroll
      for (int q = 0; q < 4; ++q) {
        const float4 v = *(const float4*)(ep + q * 4);
        es[q*4+0]=v.x; es[q*4+1]=v.y; es[q*4+2]=v.z; es[q*4+3]=v.w;
      }
#pragma unroll
      for (int t = 0; t < 4; ++t) {
        float p = 0.f;
#pragma unroll
        for (int u = 0; u < 16; ++u) p = fmaf(x[t][u], es[u], p);
        pbuf[wave][ei * 4 + t][lane] = p;
      }
    }
    // intra-wave transpose reduce (compiler inserts lgkm waits; no cross-wave use)
    const int pr = lane & 31, hf = lane >> 5;
    const float* src = &pbuf[wave][pr][hf * 32];
    float4 s4 = make_float4(0.f, 0.f, 0.f, 0.f);
#pragma unroll
    for (int j = 0; j < 8; ++j) {
      const float4 v = *(const float4*)(src + j * 4);
      s4.x += v.x; s4.y += v.y; s4.z += v.z; s4.w += v.w;
    }
    float s = (s4.x + s4.y) + (s4.z + s4.w);
    s += __shfl_xor(s, 32, 64);
    if (hf == 0) aff[wave * 4 + (pr & 3)][g * 8 + (pr >> 2)] = s;
  }

  if (lane < 4) {
    const int tok = tok0 + lane;
    float af[NEXP];
#pragma unroll
    for (int e2 = 0; e2 < NEXP; ++e2)
      af[e2] = sigmoidf_(aff[wave * 4 + lane][e2]);
    float sc[NROUTE];
#pragma unroll
    for (int e2 = 0; e2 < NROUTE; ++e2) sc[e2] = af[e2] + bias[e2];
    unsigned used = 0u;
    int idx[6];
#pragma unroll
    for (int j = 0; j < TOPK; ++j) {
      float bv = -1e30f; int best = 0;
#pragma unroll
      for (int e2 = 0; e2 < NROUTE; ++e2)
        if (!((used >> e2) & 1u) && sc[e2] > bv) { bv = sc[e2]; best = e2; }
      used |= (1u << best);
      idx[j] = best;
    }
    idx[4] = 30; idx[5] = 31;
#pragma unroll
    for (int j = 0; j < 6; ++j) {
      out_sel[(size_t)tok * 6 + j] = (float)idx[j];
      w6[(size_t)tok * 6 + j] = af[idx[j]];
    }
#pragma unroll
    for (int j = 0; j < TOPK; ++j) {
      sel_e[(size_t)tok * TOPK + j] = idx[j];
      atomicAdd(&counts[j * NEXP + idx[j]], 1);
    }
  }
}

// ---------------- scan: offsets + job maps ----------------
__global__ __launch_bounds__(256) void scan_kernel(const int* __restrict__ counts,
                                                   int* __restrict__ offsets,
                                                   int4* __restrict__ jm)
{
  const int tid = threadIdx.x;
  for (int i = tid; i < NJOBS; i += 256) {
    const int4 z = make_int4(0, 0, 0, 0);
    jm[4 * NJOBS + i] = (i < 512) ? make_int4(30, i * 32, 32, 0) : z;
    jm[5 * NJOBS + i] = (i < 512) ? make_int4(31, i * 32, 32, 0) : z;
    jm[0 * NJOBS + i] = z; jm[1 * NJOBS + i] = z;
    jm[2 * NJOBS + i] = z; jm[3 * NJOBS + i] = z;
  }
  __syncthreads();
  const int r = tid >> 6, lane = tid & 63;
  if (lane == 0) {
    int off = 0, joff = 0;
    for (int e = 0; e < NROUTE; ++e) {
      const int c = counts[r * NEXP + e];
      offsets[r * NEXP + e] = off;
      const int nch = (c + 31) >> 5;
      for (int ch = 0; ch < nch; ++ch)
        jm[r * NJOBS + joff + ch] = make_int4(e, off + ch * 32, min(32, c - ch * 32), 0);
      joff += nch; off += c;
    }
  }
}

// ---------------- scatter ----------------
__global__ __launch_bounds__(256) void scatter_kernel(
    const int* __restrict__ sel_e, const float* __restrict__ w6,
    const int* __restrict__ offsets, int* __restrict__ cursor,
    int* __restrict__ list_tok, float* __restrict__ list_w)
{
  const int t = blockIdx.x * 256 + threadIdx.x;
  if (t >= NTOK) return;
#pragma unroll
  for (int j = 0; j < TOPK; ++j) {
    const int e   = sel_e[(size_t)t * TOPK + j];
    const int pos = atomicAdd(&cursor[j * NEXP + e], 1);
    const int dst = j * NTOK + offsets[j * NEXP + e] + pos;
    list_tok[dst] = t;
    list_w[dst]   = w6[(size_t)t * 6 + j];
  }
  list_tok[4 * NTOK + t] = t; list_w[4 * NTOK + t] = w6[(size_t)t * 6 + 4];
  list_tok[5 * NTOK + t] = t; list_w[5 * NTOK + t] = w6[(size_t)t * 6 + 5];
}

// ---------------- fused MFMA FFN pass ----------------
// A (X / Hs-frag) in registers; weights double-buffered in LDS; one raw
// barrier per chunk; prefetch ages through MFMA + epilogue before the wait.
template<int MODE>   // 0 = write acc, 1 = rmw acc, 2 = final fp32 out
__global__ __launch_bounds__(256) void ffn_pass(
    const u16* __restrict__ Xb, const u16* __restrict__ Kc, const u16* __restrict__ Vc,
    const int4* __restrict__ jm, const int* __restrict__ ltok,
    const float* __restrict__ lw, u16* __restrict__ acc, float* __restrict__ out)
{
  __shared__ __align__(16) u16 Ks[2][16384];   // 2 x 32KB weight chunks
  __shared__ __align__(16) u16 Hs[4096];       // 8KB silu(h) tile
  __shared__ int   s_tok[TS];
  __shared__ float s_w[TS];

  const int bid = blockIdx.x;
  const int4 J = jm[(bid & 7) * (NJOBS / 8) + (bid >> 3)];
  const int nrow = J.z;
  if (nrow == 0) return;
  const int e = J.x, base = J.y;
  const int tid = threadIdx.x;
  const int wid = tid >> 6, lane = tid & 63;
  const int l31 = lane & 31, khalf = lane >> 5;
  const int wn = wid;
  const int sx = l31 & 15;

  const u16* kb = Kc + (size_t)e * 8 * 16384;
  const u16* vb = Vc + (size_t)e * 8 * 16384;
  const int ssrc = (wid * 8) * 512 + lane * 8;

  #define STAGE(src_, dst_) do { \
    _Pragma("unroll") \
    for (int u_ = 0; u_ < 8; ++u_) \
      gload16((src_) + ssrc + u_ * 512, (dst_) + (wid * 8 + u_) * 512); } while (0)

  STAGE(kb, Ks[0]);                      // prefetch K chunk 0 (ages thru barrier)

  if (tid < TS) {
    int t = 0; float w = 0.f;
    if (tid < nrow) { t = ltok[base + tid]; w = lw[base + tid]; }
    s_tok[tid] = t; s_w[tid] = w;
  }
  lgkm_bar();

  const u16* Xrow = Xb + (size_t)s_tok[l31] * DDIM;

  f32x16 accv;
#pragma unroll
  for (int i = 0; i < 16; ++i) accv[i] = 0.f;

  // ---- GEMM1: Hs[32][128] = X @ keys[e] ----
  for (int kc = 0; kc < 8; ++kc) {
    wait_bar0();                          // Ks[kc&1] resident, all waves aligned
    uint4 a[8], b[8];
    const u16* kbuf = Ks[kc & 1];
#pragma unroll
    for (int s = 0; s < 8; ++s)
      a[s] = *(const uint4*)(Xrow + kc * 128 + ((s * 2 + khalf) << 3));
#pragma unroll
    for (int s = 0; s < 8; ++s)
      b[s] = *(const uint4*)(kbuf + (wn * 32 + l31) * 128 + (((s * 2 + khalf) ^ sx) << 3));
    if (kc < 7) STAGE(kb + (kc + 1) * 16384, Ks[(kc + 1) & 1]);
    else        STAGE(vb, Ks[0]);         // prefetch V chunk 0 -> Ks[(7+1)&1]
#pragma unroll
    for (int s = 0; s < 8; ++s) accv = mfma32(a[s], b[s], accv);
  }

  // silu * w -> Hs (bf16, swizzled); V(0) prefetch stays in flight
  {
    const int hcol = wn * 32 + l31;
#pragma unroll
    for (int r = 0; r < 16; ++r) {
      const int row = (r & 3) + 8 * (r >> 2) + 4 * khalf;
      float v = accv[r];
      v = v / (1.f + expf(-v)) * s_w[row];
      Hs[row * 128 + ((((hcol >> 3) ^ (row & 15)) << 3) | (hcol & 7))] = f2bf(v);
    }
  }
  lgkm_bar();

  // hoist GEMM2 A fragments from Hs
  uint4 a2[8];
#pragma unroll
  for (int s = 0; s < 8; ++s)
    a2[s] = *(const uint4*)(Hs + l31 * 128 + (((s * 2 + khalf) ^ sx) << 3));

  unsigned obase[16]; bool oval[16];
#pragma unroll
  for (int r = 0; r < 16; ++r) {
    const int row = (r & 3) + 8 * (r >> 2) + 4 * khalf;
    oval[r] = row < nrow;
    obase[r] = (unsigned)s_tok[row] * DDIM;
  }

  // ---- GEMM2: out (+)= Hs @ values[e] ----
  for (int dc = 0; dc < 8; ++dc) {
    wait_bar0();                          // Ks[dc&1] (V chunk dc) resident
    uint4 b[8];
    const u16* vbuf = Ks[dc & 1];
#pragma unroll
    for (int s = 0; s < 8; ++s)
      b[s] = *(const uint4*)(vbuf + (wn * 32 + l31) * 128 + (((s * 2 + khalf) ^ sx) << 3));
    if (dc < 7) STAGE(vb + (dc + 1) * 16384, Ks[(dc + 1) & 1]);
    f32x16 o;
#pragma unroll
    for (int i = 0; i < 16; ++i) o[i] = 0.f;
#pragma unroll
    for (int s = 0; s < 8; ++s) o = mfma32(a2[s], b[s], o);

    const int col = dc * 128 + wn * 32 + l31;
#pragma unroll
    for (int r = 0; r < 16; ++r) {
      if (oval[r]) {
        const size_t p = (size_t)obase[r] + col;
        if (MODE == 0)      acc[p] = f2bf(o[r]);
        else if (MODE == 1) acc[p] = f2bf(bf2f(acc[p]) + o[r]);
        else                out[p] = bf2f(acc[p]) + o[r];
      }
    }
  }
  #undef STAGE
}

extern "C" void kernel_launch(void* const* d_in, const int* in_sizes, int n_in,
                              void* d_out, int out_size, void* d_ws, size_t ws_size,
                              hipStream_t stream)
{
  const float* X    = (const float*)d_in[0];
  const float* SI   = (const float*)d_in[1];
  const float* keys = (const float*)d_in[2];
  const float* vals = (const float*)d_in[3];
  const float* ES   = (const float*)d_in[4];
  const float* bias = (const float*)d_in[5];
  float* out = (float*)d_out;
  float* out_sel = out + (size_t)NTOK * DDIM;

  char* ws = (char*)d_ws;
  int*   counts   = (int*)(ws + 0);
  int*   cursor   = (int*)(ws + 512);
  int*   offsets  = (int*)(ws + 1024);
  int4*  jm       = (int4*)(ws + 2048);
  int*   list_tok = (int*)(ws + 57344);
  float* list_w   = (float*)(ws + 450560);
  float* w6       = (float*)(ws + 843776);
  int*   sel_e    = (int*)(ws + 1236992);
  u16*   Xb       = (u16*)(ws + 1507328);
  u16*   Kc       = (u16*)(ws + 35061760);
  u16*   Vc       = (u16*)(ws + 43450368);
  u16*   acc      = (u16*)(ws + 51838976);

  hipMemsetAsync(counts, 0, 1024, stream);

  cvt_x_kernel<<<(NTOK * DDIM) / (256 * 16), 256, 0, stream>>>(X, Xb);
  prep_k_kernel<<<dim3(8, NEXP), 256, 0, stream>>>(keys, Kc);
  prep_v_kernel<<<dim3(8, NEXP), 256, 0, stream>>>(vals, Vc);

  router_kernel<<<NTOK / 16, 256, 0, stream>>>(SI, ES, bias, out_sel, w6, sel_e, counts);
  scan_kernel<<<1, 256, 0, stream>>>(counts, offsets, jm);
  scatter_kernel<<<NTOK / 256, 256, 0, stream>>>(sel_e, w6, offsets, cursor, list_tok, list_w);

  // order: e30 (write acc) -> e31, rank0, rank1, rank2 (rmw) -> rank3 (final fp32)
  ffn_pass<0><<<NJOBS, 256, 0, stream>>>(Xb, Kc, Vc, jm + 4 * NJOBS,
      list_tok + 4 * NTOK, list_w + 4 * NTOK, acc, out);
  ffn_pass<1><<<NJOBS, 256, 0, stream>>>(Xb, Kc, Vc, jm + 5 * NJOBS,
      list_tok + 5 * NTOK, list_w + 5 * NTOK, acc, out);
  ffn_pass<1><<<NJOBS, 256, 0, stream>>>(Xb, Kc, Vc, jm + 0 * NJOBS,
      list_tok + 0 * NTOK, list_w + 0 * NTOK, acc, out);
  ffn_pass<1><<<NJOBS, 256, 0, stream>>>(Xb, Kc, Vc, jm + 1 * NJOBS,
      list_tok + 1 * NTOK, list_w + 1 * NTOK, acc, out);
  ffn_pass<1><<<NJOBS, 256, 0, stream>>>(Xb, Kc, Vc, jm + 2 * NJOBS,
      list_tok + 2 * NTOK, list_w + 2 * NTOK, acc, out);
  ffn_pass<2><<<NJOBS, 256, 0, stream>>>(Xb, Kc, Vc, jm + 3 * NJOBS,
      list_tok + 3 * NTOK, list_w + 3 * NTOK, acc, out);
}

// Round 5
// 710.849 us; speedup vs baseline: 1.3457x; 1.3457x over previous
//
#include <hip/hip_runtime.h>
#include <math.h>

#define NTOK   16384
#define DDIM   1024
#define HDIM   128
#define NEXP   32
#define NROUTE 30
#define TOPK   4
#define TS     32
#define NJOBS  544          // 8*68

typedef short bf16x8 __attribute__((ext_vector_type(8)));
typedef float f32x16 __attribute__((ext_vector_type(16)));
typedef unsigned short u16;

__device__ __forceinline__ float sigmoidf_(float x) { return 1.f / (1.f + expf(-x)); }

__device__ __forceinline__ u16 f2bf(float x) {
  unsigned u = __float_as_uint(x);
  u += 0x7fffu + ((u >> 16) & 1u);
  return (u16)(u >> 16);
}
__device__ __forceinline__ float bf2f(u16 v) {
  return __uint_as_float(((unsigned)v) << 16);
}

__device__ __forceinline__ f32x16 mfma32(uint4 a, uint4 b, f32x16 c) {
  union { uint4 u; bf16x8 h; } A, B;
  A.u = a; B.u = b;
  return __builtin_amdgcn_mfma_f32_32x32x16_bf16(A.h, B.h, c, 0, 0, 0);
}

__device__ __forceinline__ void gload16(const void* g, void* l) {
  __builtin_amdgcn_global_load_lds(
      (const __attribute__((address_space(1))) unsigned int*)g,
      (__attribute__((address_space(3))) unsigned int*)l, 16, 0, 0);
}

// lgkm-only barrier: LDS writes visible; vmem (incl. register prefetch) stays in flight.
__device__ __forceinline__ void lgkm_bar() {
  asm volatile("s_waitcnt lgkmcnt(0)\ns_barrier" ::: "memory");
}

// ---------------- prep: X fp32 -> bf16 ----------------
__global__ __launch_bounds__(256) void cvt_x_kernel(const float* __restrict__ X,
                                                    u16* __restrict__ Xb)
{
  const size_t base = ((size_t)blockIdx.x * 256 + threadIdx.x) * 16;
  u16 v[16];
#pragma unroll
  for (int i = 0; i < 4; ++i) {
    const float4 f = *(const float4*)(X + base + i * 4);
    v[i*4+0] = f2bf(f.x); v[i*4+1] = f2bf(f.y);
    v[i*4+2] = f2bf(f.z); v[i*4+3] = f2bf(f.w);
  }
  *(uint4*)(Xb + base) = *(const uint4*)v;
  *(uint4*)(Xb + base + 8) = *(const uint4*)(v + 8);
}

// ---- prep: keys [E][D][H] -> fragment-major Kf[e][kc][s][wn][lane][8] ----
// frag element: K[e][kc*128 + (s*2+khalf)*8 + j][wn*32 + l31], lane = khalf*32+l31
__global__ __launch_bounds__(256) void prep_k_kernel(const float* __restrict__ K,
                                                     u16* __restrict__ Kf)
{
  __shared__ float t[128][129];
  const int kc = blockIdx.x, e = blockIdx.y, tid = threadIdx.x;
#pragma unroll
  for (int i = 0; i < 64; ++i) {
    const int g = tid + i * 256;
    const int d = g >> 7, h = g & 127;
    t[d][h] = K[((size_t)e * DDIM + kc * 128 + d) * HDIM + h];
  }
  __syncthreads();
  u16* dst = Kf + ((size_t)e * 8 + kc) * 16384;
#pragma unroll
  for (int i = 0; i < 64; ++i) {
    const int f = tid + i * 256;
    const int s = f >> 11, wn = (f >> 9) & 3, l = (f >> 3) & 63, j = f & 7;
    const int khalf = l >> 5, l31 = l & 31;
    dst[f] = f2bf(t[(s * 2 + khalf) * 8 + j][wn * 32 + l31]);
  }
}

// ---- prep: values [E][H][D] -> fragment-major Vf[e][dc][s][wn][lane][8] ----
// frag element: V[e][(s*2+khalf)*8 + j][dc*128 + wn*32 + l31]
__global__ __launch_bounds__(256) void prep_v_kernel(const float* __restrict__ V,
                                                     u16* __restrict__ Vf)
{
  __shared__ float t[128][129];
  const int dc = blockIdx.x, e = blockIdx.y, tid = threadIdx.x;
#pragma unroll
  for (int i = 0; i < 64; ++i) {
    const int g = tid + i * 256;
    const int h = g >> 7, dl = g & 127;
    t[h][dl] = V[((size_t)e * HDIM + h) * DDIM + dc * 128 + dl];
  }
  __syncthreads();
  u16* dst = Vf + ((size_t)e * 8 + dc) * 16384;
#pragma unroll
  for (int i = 0; i < 64; ++i) {
    const int f = tid + i * 256;
    const int s = f >> 11, wn = (f >> 9) & 3, l = (f >> 3) & 63, j = f & 7;
    const int khalf = l >> 5, l31 = l & 31;
    dst[f] = f2bf(t[(s * 2 + khalf) * 8 + j][wn * 32 + l31]);
  }
}

// ---------------- router: ES staged in LDS + pbuf transpose reduce ----------------
__global__ __launch_bounds__(256) void router_kernel(
    const float* __restrict__ SI, const float* __restrict__ ES,
    const float* __restrict__ bias, float* __restrict__ out_sel,
    float* __restrict__ w6, int* __restrict__ sel_e, int* __restrict__ counts)
{
  __shared__ float es_lds[8 * 1024];  // 32KB: 8 experts fp32
  __shared__ float pbuf[4][32][68];
  __shared__ float aff[16][33];
  const int tid = threadIdx.x, wave = tid >> 6, lane = tid & 63;
  const int tok0 = blockIdx.x * 16 + wave * 4;

  float x[4][16];
#pragma unroll
  for (int t = 0; t < 4; ++t) {
    const float* xp = SI + (size_t)(tok0 + t) * DDIM + lane * 16;
#pragma unroll
    for (int q = 0; q < 4; ++q) {
      const float4 v = *(const float4*)(xp + q * 4);
      x[t][q*4+0]=v.x; x[t][q*4+1]=v.y; x[t][q*4+2]=v.z; x[t][q*4+3]=v.w;
    }
  }

  for (int g = 0; g < 4; ++g) {
    __syncthreads();    // previous group's es_lds reads done
#pragma unroll
    for (int u = 0; u < 8; ++u)
      gload16(ES + g * 8192 + (wave * 8 + u) * 256 + lane * 4,
              es_lds + (wave * 8 + u) * 256);
    __syncthreads();    // staged (auto vmcnt0) + visible

#pragma unroll
    for (int ei = 0; ei < 8; ++ei) {
      float es[16];
      const float* ep = es_lds + ei * 1024 + lane * 16;
#pragma unroll
      for (int q = 0; q < 4; ++q) {
        const float4 v = *(const float4*)(ep + q * 4);
        es[q*4+0]=v.x; es[q*4+1]=v.y; es[q*4+2]=v.z; es[q*4+3]=v.w;
      }
#pragma unroll
      for (int t = 0; t < 4; ++t) {
        float p = 0.f;
#pragma unroll
        for (int u = 0; u < 16; ++u) p = fmaf(x[t][u], es[u], p);
        pbuf[wave][ei * 4 + t][lane] = p;
      }
    }
    const int pr = lane & 31, hf = lane >> 5;
    const float* src = &pbuf[wave][pr][hf * 32];
    float4 s4 = make_float4(0.f, 0.f, 0.f, 0.f);
#pragma unroll
    for (int j = 0; j < 8; ++j) {
      const float4 v = *(const float4*)(src + j * 4);
      s4.x += v.x; s4.y += v.y; s4.z += v.z; s4.w += v.w;
    }
    float s = (s4.x + s4.y) + (s4.z + s4.w);
    s += __shfl_xor(s, 32, 64);
    if (hf == 0) aff[wave * 4 + (pr & 3)][g * 8 + (pr >> 2)] = s;
  }

  if (lane < 4) {
    const int tok = tok0 + lane;
    float af[NEXP];
#pragma unroll
    for (int e2 = 0; e2 < NEXP; ++e2)
      af[e2] = sigmoidf_(aff[wave * 4 + lane][e2]);
    float sc[NROUTE];
#pragma unroll
    for (int e2 = 0; e2 < NROUTE; ++e2) sc[e2] = af[e2] + bias[e2];
    unsigned used = 0u;
    int idx[6];
#pragma unroll
    for (int j = 0; j < TOPK; ++j) {
      float bv = -1e30f; int best = 0;
#pragma unroll
      for (int e2 = 0; e2 < NROUTE; ++e2)
        if (!((used >> e2) & 1u) && sc[e2] > bv) { bv = sc[e2]; best = e2; }
      used |= (1u << best);
      idx[j] = best;
    }
    idx[4] = 30; idx[5] = 31;
#pragma unroll
    for (int j = 0; j < 6; ++j) {
      out_sel[(size_t)tok * 6 + j] = (float)idx[j];
      w6[(size_t)tok * 6 + j] = af[idx[j]];
    }
#pragma unroll
    for (int j = 0; j < TOPK; ++j) {
      sel_e[(size_t)tok * TOPK + j] = idx[j];
      atomicAdd(&counts[j * NEXP + idx[j]], 1);
    }
  }
}

// ---------------- scan: offsets + job maps ----------------
__global__ __launch_bounds__(256) void scan_kernel(const int* __restrict__ counts,
                                                   int* __restrict__ offsets,
                                                   int4* __restrict__ jm)
{
  const int tid = threadIdx.x;
  for (int i = tid; i < NJOBS; i += 256) {
    const int4 z = make_int4(0, 0, 0, 0);
    jm[4 * NJOBS + i] = (i < 512) ? make_int4(30, i * 32, 32, 0) : z;
    jm[5 * NJOBS + i] = (i < 512) ? make_int4(31, i * 32, 32, 0) : z;
    jm[0 * NJOBS + i] = z; jm[1 * NJOBS + i] = z;
    jm[2 * NJOBS + i] = z; jm[3 * NJOBS + i] = z;
  }
  __syncthreads();
  const int r = tid >> 6, lane = tid & 63;
  if (lane == 0) {
    int off = 0, joff = 0;
    for (int e = 0; e < NROUTE; ++e) {
      const int c = counts[r * NEXP + e];
      offsets[r * NEXP + e] = off;
      const int nch = (c + 31) >> 5;
      for (int ch = 0; ch < nch; ++ch)
        jm[r * NJOBS + joff + ch] = make_int4(e, off + ch * 32, min(32, c - ch * 32), 0);
      joff += nch; off += c;
    }
  }
}

// ---------------- scatter ----------------
__global__ __launch_bounds__(256) void scatter_kernel(
    const int* __restrict__ sel_e, const float* __restrict__ w6,
    const int* __restrict__ offsets, int* __restrict__ cursor,
    int* __restrict__ list_tok, float* __restrict__ list_w)
{
  const int t = blockIdx.x * 256 + threadIdx.x;
  if (t >= NTOK) return;
#pragma unroll
  for (int j = 0; j < TOPK; ++j) {
    const int e   = sel_e[(size_t)t * TOPK + j];
    const int pos = atomicAdd(&cursor[j * NEXP + e], 1);
    const int dst = j * NTOK + offsets[j * NEXP + e] + pos;
    list_tok[dst] = t;
    list_w[dst]   = w6[(size_t)t * 6 + j];
  }
  list_tok[4 * NTOK + t] = t; list_w[4 * NTOK + t] = w6[(size_t)t * 6 + 4];
  list_tok[5 * NTOK + t] = t; list_w[5 * NTOK + t] = w6[(size_t)t * 6 + 5];
}

// ---------------- fused MFMA FFN pass: register-direct weights ----------------
// B-fragments loaded straight from fragment-major global layout into VGPRs,
// double-buffered one chunk ahead. No LDS for weights -> no barriers in the
// GEMM loops. Only Hs (8KB) round-trips through LDS with lgkm-only barriers.
__device__ __forceinline__ void loadb(uint4* b, const u16* __restrict__ base,
                                      int c, int wid, int lane) {
#pragma unroll
  for (int s = 0; s < 8; ++s)
    b[s] = *(const uint4*)(base + (size_t)(((c * 8 + s) * 4 + wid) * 512) + lane * 8);
}

template<int MODE>   // 0 = write acc, 1 = rmw acc, 2 = final fp32 out
__global__ __launch_bounds__(256) void ffn_pass(
    const u16* __restrict__ Xb, const u16* __restrict__ Kf, const u16* __restrict__ Vf,
    const int4* __restrict__ jm, const int* __restrict__ ltok,
    const float* __restrict__ lw, u16* __restrict__ acc, float* __restrict__ out)
{
  __shared__ __align__(16) u16 Hs[32 * 128];   // 8KB
  __shared__ int   s_tok[TS];
  __shared__ float s_w[TS];

  const int bid = blockIdx.x;
  const int4 J = jm[(bid & 7) * (NJOBS / 8) + (bid >> 3)];
  const int nrow = J.z;
  if (nrow == 0) return;
  const int e = J.x, base = J.y;
  const int tid = threadIdx.x;
  const int wid = tid >> 6, lane = tid & 63;
  const int l31 = lane & 31, khalf = lane >> 5;
  const int sx = l31 & 15;

  const u16* Kf_e = Kf + (size_t)e * 131072;
  const u16* Vf_e = Vf + (size_t)e * 131072;

  uint4 bb[2][8];
  loadb(bb[0], Kf_e, 0, wid, lane);   // prefetch K chunk 0 (stays in flight)

  if (tid < TS) {
    int t = 0; float w = 0.f;
    if (tid < nrow) { t = ltok[base + tid]; w = lw[base + tid]; }
    s_tok[tid] = t; s_w[tid] = w;
  }
  lgkm_bar();                          // s_tok visible; prefetch NOT drained

  const u16* Xrow = Xb + (size_t)s_tok[l31] * DDIM;

  f32x16 accv;
#pragma unroll
  for (int i = 0; i < 16; ++i) accv[i] = 0.f;

  // ---- GEMM1: Hs[32][128] = X @ keys[e] ----
#pragma unroll
  for (int kc = 0; kc < 8; ++kc) {
    const int cur = kc & 1;
    if (kc < 7) loadb(bb[cur ^ 1], Kf_e, kc + 1, wid, lane);
    else        loadb(bb[cur ^ 1], Vf_e, 0, wid, lane);   // V chunk 0 prefetch
    uint4 a[8];
#pragma unroll
    for (int s = 0; s < 8; ++s)
      a[s] = *(const uint4*)(Xrow + kc * 128 + (s * 2 + khalf) * 8);
#pragma unroll
    for (int s = 0; s < 8; ++s) accv = mfma32(a[s], bb[cur][s], accv);
  }

  // silu * w -> Hs (bf16, XOR-swizzled rows)
  {
    const int hcol = wid * 32 + l31;
#pragma unroll
    for (int r = 0; r < 16; ++r) {
      const int row = (r & 3) + 8 * (r >> 2) + 4 * khalf;
      float v = accv[r];
      v = v / (1.f + expf(-v)) * s_w[row];
      Hs[row * 128 + ((((hcol >> 3) ^ (row & 15)) << 3) | (hcol & 7))] = f2bf(v);
    }
  }
  lgkm_bar();                          // Hs visible; V prefetch still in flight

  uint4 a2[8];
#pragma unroll
  for (int s = 0; s < 8; ++s)
    a2[s] = *(const uint4*)(Hs + l31 * 128 + (((s * 2 + khalf) ^ sx) << 3));

  unsigned obase[16]; bool oval[16];
#pragma unroll
  for (int r = 0; r < 16; ++r) {
    const int row = (r & 3) + 8 * (r >> 2) + 4 * khalf;
    oval[r] = row < nrow;
    obase[r] = (unsigned)s_tok[row] * DDIM;
  }

  // ---- GEMM2: out (+)= Hs @ values[e] ----
#pragma unroll
  for (int dc = 0; dc < 8; ++dc) {
    const int cur = dc & 1;
    if (dc < 7) loadb(bb[cur ^ 1], Vf_e, dc + 1, wid, lane);
    f32x16 o;
#pragma unroll
    for (int i = 0; i < 16; ++i) o[i] = 0.f;
#pragma unroll
    for (int s = 0; s < 8; ++s) o = mfma32(a2[s], bb[cur][s], o);

    const int col = dc * 128 + wid * 32 + l31;
#pragma unroll
    for (int r = 0; r < 16; ++r) {
      if (oval[r]) {
        const size_t p = (size_t)obase[r] + col;
        if (MODE == 0)      acc[p] = f2bf(o[r]);
        else if (MODE == 1) acc[p] = f2bf(bf2f(acc[p]) + o[r]);
        else                out[p] = bf2f(acc[p]) + o[r];
      }
    }
  }
}

extern "C" void kernel_launch(void* const* d_in, const int* in_sizes, int n_in,
                              void* d_out, int out_size, void* d_ws, size_t ws_size,
                              hipStream_t stream)
{
  const float* X    = (const float*)d_in[0];
  const float* SI   = (const float*)d_in[1];
  const float* keys = (const float*)d_in[2];
  const float* vals = (const float*)d_in[3];
  const float* ES   = (const float*)d_in[4];
  const float* bias = (const float*)d_in[5];
  float* out = (float*)d_out;
  float* out_sel = out + (size_t)NTOK * DDIM;

  char* ws = (char*)d_ws;
  int*   counts   = (int*)(ws + 0);
  int*   cursor   = (int*)(ws + 512);
  int*   offsets  = (int*)(ws + 1024);
  int4*  jm       = (int4*)(ws + 2048);
  int*   list_tok = (int*)(ws + 57344);
  float* list_w   = (float*)(ws + 450560);
  float* w6       = (float*)(ws + 843776);
  int*   sel_e    = (int*)(ws + 1236992);
  u16*   Xb       = (u16*)(ws + 1507328);
  u16*   Kf       = (u16*)(ws + 35061760);
  u16*   Vf       = (u16*)(ws + 43450368);
  u16*   acc      = (u16*)(ws + 51838976);

  hipMemsetAsync(counts, 0, 1024, stream);

  cvt_x_kernel<<<(NTOK * DDIM) / (256 * 16), 256, 0, stream>>>(X, Xb);
  prep_k_kernel<<<dim3(8, NEXP), 256, 0, stream>>>(keys, Kf);
  prep_v_kernel<<<dim3(8, NEXP), 256, 0, stream>>>(vals, Vf);

  router_kernel<<<NTOK / 16, 256, 0, stream>>>(SI, ES, bias, out_sel, w6, sel_e, counts);
  scan_kernel<<<1, 256, 0, stream>>>(counts, offsets, jm);
  scatter_kernel<<<NTOK / 256, 256, 0, stream>>>(sel_e, w6, offsets, cursor, list_tok, list_w);

  // order: e30 (write acc) -> e31, rank0, rank1, rank2 (rmw) -> rank3 (final fp32)
  ffn_pass<0><<<NJOBS, 256, 0, stream>>>(Xb, Kf, Vf, jm + 4 * NJOBS,
      list_tok + 4 * NTOK, list_w + 4 * NTOK, acc, out);
  ffn_pass<1><<<NJOBS, 256, 0, stream>>>(Xb, Kf, Vf, jm + 5 * NJOBS,
      list_tok + 5 * NTOK, list_w + 5 * NTOK, acc, out);
  ffn_pass<1><<<NJOBS, 256, 0, stream>>>(Xb, Kf, Vf, jm + 0 * NJOBS,
      list_tok + 0 * NTOK, list_w + 0 * NTOK, acc, out);
  ffn_pass<1><<<NJOBS, 256, 0, stream>>>(Xb, Kf, Vf, jm + 1 * NJOBS,
      list_tok + 1 * NTOK, list_w + 1 * NTOK, acc, out);
  ffn_pass<1><<<NJOBS, 256, 0, stream>>>(Xb, Kf, Vf, jm + 2 * NJOBS,
      list_tok + 2 * NTOK, list_w + 2 * NTOK, acc, out);
  ffn_pass<2><<<NJOBS, 256, 0, stream>>>(Xb, Kf, Vf, jm + 3 * NJOBS,
      list_tok + 3 * NTOK, list_w + 3 * NTOK, acc, out);
}

// Round 6
// 500.894 us; speedup vs baseline: 1.9097x; 1.4192x over previous
//
#include <hip/hip_runtime.h>
#include <math.h>

#define NTOK   16384
#define DDIM   1024
#define HDIM   128
#define NEXP   32
#define NROUTE 30
#define TOPK   4
#define TS     64
#define NJOBS_F 1696        // 8*212 fused job slots
#define CPX_F   212
#define NJOBS_S 288         // 8*36 per serial section
#define CPX_S   36
#define SLAB   ((size_t)NTOK * DDIM)

typedef short bf16x8 __attribute__((ext_vector_type(8)));
typedef float f32x16 __attribute__((ext_vector_type(16)));
typedef unsigned short u16;

__device__ __forceinline__ float sigmoidf_(float x) { return 1.f / (1.f + expf(-x)); }

__device__ __forceinline__ u16 f2bf(float x) {
  unsigned u = __float_as_uint(x);
  u += 0x7fffu + ((u >> 16) & 1u);
  return (u16)(u >> 16);
}
__device__ __forceinline__ float bf2f(u16 v) {
  return __uint_as_float(((unsigned)v) << 16);
}

__device__ __forceinline__ f32x16 mfma32(uint4 a, uint4 b, f32x16 c) {
  union { uint4 u; bf16x8 h; } A, B;
  A.u = a; B.u = b;
  return __builtin_amdgcn_mfma_f32_32x32x16_bf16(A.h, B.h, c, 0, 0, 0);
}

// lgkm-only barrier: LDS writes visible; vmem prefetch stays in flight.
__device__ __forceinline__ void lgkm_bar() {
  asm volatile("s_waitcnt lgkmcnt(0)\ns_barrier" ::: "memory");
}

// ---------------- prep: X fp32 -> bf16 ----------------
__global__ __launch_bounds__(256) void cvt_x_kernel(const float* __restrict__ X,
                                                    u16* __restrict__ Xb)
{
  const size_t base = ((size_t)blockIdx.x * 256 + threadIdx.x) * 16;
  u16 v[16];
#pragma unroll
  for (int i = 0; i < 4; ++i) {
    const float4 f = *(const float4*)(X + base + i * 4);
    v[i*4+0] = f2bf(f.x); v[i*4+1] = f2bf(f.y);
    v[i*4+2] = f2bf(f.z); v[i*4+3] = f2bf(f.w);
  }
  *(uint4*)(Xb + base) = *(const uint4*)v;
  *(uint4*)(Xb + base + 8) = *(const uint4*)(v + 8);
}

// ---- prep: keys [E][D][H] -> fragment-major Kf[e][kc][s][wn][lane][8] ----
__global__ __launch_bounds__(256) void prep_k_kernel(const float* __restrict__ K,
                                                     u16* __restrict__ Kf)
{
  __shared__ float t[128][129];
  const int kc = blockIdx.x, e = blockIdx.y, tid = threadIdx.x;
#pragma unroll
  for (int i = 0; i < 64; ++i) {
    const int g = tid + i * 256;
    const int d = g >> 7, h = g & 127;
    t[d][h] = K[((size_t)e * DDIM + kc * 128 + d) * HDIM + h];
  }
  __syncthreads();
  u16* dst = Kf + ((size_t)e * 8 + kc) * 16384;
#pragma unroll
  for (int i = 0; i < 64; ++i) {
    const int f = tid + i * 256;
    const int s = f >> 11, wn = (f >> 9) & 3, l = (f >> 3) & 63, j = f & 7;
    const int khalf = l >> 5, l31 = l & 31;
    dst[f] = f2bf(t[(s * 2 + khalf) * 8 + j][wn * 32 + l31]);
  }
}

// ---- prep: values [E][H][D] -> fragment-major Vf[e][dc][s][wn][lane][8] ----
__global__ __launch_bounds__(256) void prep_v_kernel(const float* __restrict__ V,
                                                     u16* __restrict__ Vf)
{
  __shared__ float t[128][129];
  const int dc = blockIdx.x, e = blockIdx.y, tid = threadIdx.x;
#pragma unroll
  for (int i = 0; i < 64; ++i) {
    const int g = tid + i * 256;
    const int h = g >> 7, dl = g & 127;
    t[h][dl] = V[((size_t)e * HDIM + h) * DDIM + dc * 128 + dl];
  }
  __syncthreads();
  u16* dst = Vf + ((size_t)e * 8 + dc) * 16384;
#pragma unroll
  for (int i = 0; i < 64; ++i) {
    const int f = tid + i * 256;
    const int s = f >> 11, wn = (f >> 9) & 3, l = (f >> 3) & 63, j = f & 7;
    const int khalf = l >> 5, l31 = l & 31;
    dst[f] = f2bf(t[(s * 2 + khalf) * 8 + j][wn * 32 + l31]);
  }
}

// ---------------- router: direct ES loads, stride-65 pbuf, no barriers ----------------
__global__ __launch_bounds__(256, 4) void router_kernel(
    const float* __restrict__ SI, const float* __restrict__ ES,
    const float* __restrict__ bias, float* __restrict__ out_sel,
    float* __restrict__ w6, int* __restrict__ sel_e, int* __restrict__ counts)
{
  __shared__ float pbuf[4][32][65];   // wave-private; stride 65 -> conflict-free
  __shared__ float aff[16][33];
  const int tid = threadIdx.x, wave = tid >> 6, lane = tid & 63;
  const int tok0 = blockIdx.x * 16 + wave * 4;

  float x[4][16];
#pragma unroll
  for (int t = 0; t < 4; ++t) {
    const float* xp = SI + (size_t)(tok0 + t) * DDIM + lane * 16;
#pragma unroll
    for (int q = 0; q < 4; ++q) {
      const float4 v = *(const float4*)(xp + q * 4);
      x[t][q*4+0]=v.x; x[t][q*4+1]=v.y; x[t][q*4+2]=v.z; x[t][q*4+3]=v.w;
    }
  }

#pragma unroll
  for (int g = 0; g < 4; ++g) {
#pragma unroll
    for (int ei = 0; ei < 8; ++ei) {
      const int e = g * 8 + ei;
      float es[16];
      const float* ep = ES + (size_t)e * DDIM + lane * 16;
#pragma unroll
      for (int q = 0; q < 4; ++q) {
        const float4 v = *(const float4*)(ep + q * 4);
        es[q*4+0]=v.x; es[q*4+1]=v.y; es[q*4+2]=v.z; es[q*4+3]=v.w;
      }
#pragma unroll
      for (int t = 0; t < 4; ++t) {
        float p = 0.f;
#pragma unroll
        for (int u = 0; u < 16; ++u) p = fmaf(x[t][u], es[u], p);
        pbuf[wave][ei * 4 + t][lane] = p;
      }
    }
    // intra-wave transpose reduce (same-wave LDS ordering)
    const int pr = lane & 31, hf = lane >> 5;
    const float* src = &pbuf[wave][pr][hf * 32];
    float4 s4 = make_float4(0.f, 0.f, 0.f, 0.f);
#pragma unroll
    for (int j = 0; j < 8; ++j) {
      const float4 v = *(const float4*)(src + j * 4);
      s4.x += v.x; s4.y += v.y; s4.z += v.z; s4.w += v.w;
    }
    float s = (s4.x + s4.y) + (s4.z + s4.w);
    s += __shfl_xor(s, 32, 64);
    if (hf == 0) aff[wave * 4 + (pr & 3)][g * 8 + (pr >> 2)] = s;
  }

  if (lane < 4) {
    const int tok = tok0 + lane;
    float af[NEXP];
#pragma unroll
    for (int e2 = 0; e2 < NEXP; ++e2)
      af[e2] = sigmoidf_(aff[wave * 4 + lane][e2]);
    float sc[NROUTE];
#pragma unroll
    for (int e2 = 0; e2 < NROUTE; ++e2) sc[e2] = af[e2] + bias[e2];
    unsigned used = 0u;
    int idx[6];
#pragma unroll
    for (int j = 0; j < TOPK; ++j) {
      float bv = -1e30f; int best = 0;
#pragma unroll
      for (int e2 = 0; e2 < NROUTE; ++e2)
        if (!((used >> e2) & 1u) && sc[e2] > bv) { bv = sc[e2]; best = e2; }
      used |= (1u << best);
      idx[j] = best;
    }
    idx[4] = 30; idx[5] = 31;
#pragma unroll
    for (int j = 0; j < 6; ++j) {
      out_sel[(size_t)tok * 6 + j] = (float)idx[j];
      w6[(size_t)tok * 6 + j] = af[idx[j]];
    }
#pragma unroll
    for (int j = 0; j < TOPK; ++j) {
      sel_e[(size_t)tok * TOPK + j] = idx[j];
      atomicAdd(&counts[j * NEXP + idx[j]], 1);
    }
  }
}

// ---------------- scan: offsets + fused (expert-major) and serial job maps ----------------
__global__ __launch_bounds__(256) void scan_kernel(const int* __restrict__ counts,
                                                   int* __restrict__ offsets,
                                                   int4* __restrict__ jm)
{
  __shared__ int c4[30][4];
  __shared__ int off4[30][4];
  __shared__ int nch[32];
  __shared__ int joff[31];
  const int tid = threadIdx.x;

  if (tid < 4) {
    int off = 0;
    for (int e = 0; e < NROUTE; ++e) {
      const int c = counts[tid * NEXP + e];
      offsets[tid * NEXP + e] = off;
      c4[e][tid] = c; off4[e][tid] = off;
      off += c;
    }
  }
  __syncthreads();
  if (tid < NROUTE) {
    int n = 0;
#pragma unroll
    for (int r = 0; r < 4; ++r) n += (c4[tid][r] + TS - 1) / TS;
    nch[tid] = n;
  }
  __syncthreads();
  if (tid == 0) {
    int run = 0;
    for (int e = 0; e < NROUTE; ++e) { joff[e] = run; run += nch[e]; }
    joff[NROUTE] = run;
  }
  __syncthreads();
  const int routed_total = joff[NROUTE];

  // fused routed entries (expert-major, ranks interleaved within expert)
  if (tid < NROUTE) {
    const int e = tid;
    int idx = joff[e];
    for (int r = 0; r < 4; ++r) {
      const int c = c4[e][r];
      for (int ch = 0; ch * TS < c; ++ch)
        jm[idx++] = make_int4(e, off4[e][r] + ch * TS, min(TS, c - ch * TS), r);
    }
  }
  // fused shared entries + padding
  for (int i = tid; i < 512; i += 256)
    jm[routed_total + i] = make_int4(30 + (i >> 8), (i & 255) * TS, TS, 4 + (i >> 8));
  for (int i = routed_total + 512 + tid; i < NJOBS_F; i += 256)
    jm[i] = make_int4(0, 0, 0, 0);

  // serial sections (fallback): routed rank r at 2048 + r*NJOBS_S
  if (tid < 4) {
    const int r = tid;
    int cnt = 0;
    int4* sec = jm + 2048 + r * NJOBS_S;
    for (int e = 0; e < NROUTE; ++e) {
      const int c = c4[e][r];
      for (int ch = 0; ch * TS < c; ++ch)
        sec[cnt++] = make_int4(e, off4[e][r] + ch * TS, min(TS, c - ch * TS), r);
    }
    for (; cnt < NJOBS_S; ++cnt) sec[cnt] = make_int4(0, 0, 0, 0);
  }
  for (int i = tid; i < 2 * NJOBS_S; i += 256) {
    const int s = i / NJOBS_S, k = i % NJOBS_S;
    jm[2048 + (4 + s) * NJOBS_S + k] =
        (k < 256) ? make_int4(30 + s, k * TS, TS, 4 + s) : make_int4(0, 0, 0, 0);
  }
}

// ---------------- scatter ----------------
__global__ __launch_bounds__(256) void scatter_kernel(
    const int* __restrict__ sel_e, const float* __restrict__ w6,
    const int* __restrict__ offsets, int* __restrict__ cursor,
    int* __restrict__ list_tok, float* __restrict__ list_w)
{
  const int t = blockIdx.x * 256 + threadIdx.x;
  if (t >= NTOK) return;
#pragma unroll
  for (int j = 0; j < TOPK; ++j) {
    const int e   = sel_e[(size_t)t * TOPK + j];
    const int pos = atomicAdd(&cursor[j * NEXP + e], 1);
    const int dst = j * NTOK + offsets[j * NEXP + e] + pos;
    list_tok[dst] = t;
    list_w[dst]   = w6[(size_t)t * 6 + j];
  }
  list_tok[4 * NTOK + t] = t; list_w[4 * NTOK + t] = w6[(size_t)t * 6 + 4];
  list_tok[5 * NTOK + t] = t; list_w[5 * NTOK + t] = w6[(size_t)t * 6 + 5];
}

// ---------------- fused MFMA FFN: TS=64, register-direct weights ----------------
__device__ __forceinline__ void loadb(uint4* b, const u16* __restrict__ base,
                                      int c, int wid, int lane) {
#pragma unroll
  for (int s = 0; s < 8; ++s)
    b[s] = *(const uint4*)(base + (size_t)(((c * 8 + s) * 4 + wid) * 512) + lane * 8);
}

// MODE: 0 = store per-rank partial, 1 = write acc, 2 = rmw acc, 3 = final fp32
template<int MODE>
__global__ __launch_bounds__(256, 2) void ffn_pass(
    const u16* __restrict__ Xb, const u16* __restrict__ Kf, const u16* __restrict__ Vf,
    const int4* __restrict__ jm, const int cpx,
    const int* __restrict__ list_tok, const float* __restrict__ list_w,
    u16* __restrict__ part, float* __restrict__ out)
{
  __shared__ __align__(16) u16 Hs[TS * 128];   // 16KB
  __shared__ int   s_tok[TS];
  __shared__ float s_w[TS];

  const int bid = blockIdx.x;
  const int4 J = jm[(bid & 7) * cpx + (bid >> 3)];
  const int nrow = J.z;
  if (nrow == 0) return;
  const int e = J.x, base = J.y, rank = J.w;
  const int tid = threadIdx.x;
  const int wid = tid >> 6, lane = tid & 63;
  const int l31 = lane & 31, khalf = lane >> 5;
  const int sx = l31 & 15;

  const u16* Kf_e = Kf + (size_t)e * 131072;
  const u16* Vf_e = Vf + (size_t)e * 131072;

  uint4 bb[2][8];
  loadb(bb[0], Kf_e, 0, wid, lane);    // prefetch K chunk 0 (stays in flight)

  {
    const int* lt = list_tok + rank * NTOK;
    const float* lww = list_w + rank * NTOK;
    if (tid < TS) {
      int t = 0; float w = 0.f;
      if (tid < nrow) { t = lt[base + tid]; w = lww[base + tid]; }
      s_tok[tid] = t; s_w[tid] = w;
    }
  }
  lgkm_bar();                           // s_tok visible; prefetch NOT drained

  const u16* Xrow0 = Xb + (size_t)s_tok[l31] * DDIM;
  const u16* Xrow1 = Xb + (size_t)s_tok[32 + l31] * DDIM;

  f32x16 acc0, acc1;
#pragma unroll
  for (int i = 0; i < 16; ++i) { acc0[i] = 0.f; acc1[i] = 0.f; }

  // ---- GEMM1: Hs[64][128] = X @ keys[e] ----
#pragma unroll
  for (int kc = 0; kc < 8; ++kc) {
    const int cur = kc & 1;
    if (kc < 7) loadb(bb[cur ^ 1], Kf_e, kc + 1, wid, lane);
    else        loadb(bb[cur ^ 1], Vf_e, 0, wid, lane);
    uint4 a0[8], a1[8];
#pragma unroll
    for (int s = 0; s < 8; ++s) {
      a0[s] = *(const uint4*)(Xrow0 + kc * 128 + (s * 2 + khalf) * 8);
      a1[s] = *(const uint4*)(Xrow1 + kc * 128 + (s * 2 + khalf) * 8);
    }
#pragma unroll
    for (int s = 0; s < 8; ++s) {
      acc0 = mfma32(a0[s], bb[cur][s], acc0);
      acc1 = mfma32(a1[s], bb[cur][s], acc1);
    }
  }

  // silu * w -> Hs (bf16, XOR-swizzled rows)
  {
    const int hcol = wid * 32 + l31;
#pragma unroll
    for (int r = 0; r < 16; ++r) {
      const int row0 = (r & 3) + 8 * (r >> 2) + 4 * khalf;
      float v0 = acc0[r];
      v0 = v0 / (1.f + expf(-v0)) * s_w[row0];
      Hs[row0 * 128 + ((((hcol >> 3) ^ (row0 & 15)) << 3) | (hcol & 7))] = f2bf(v0);
      const int row1 = row0 + 32;
      float v1 = acc1[r];
      v1 = v1 / (1.f + expf(-v1)) * s_w[row1];
      Hs[row1 * 128 + ((((hcol >> 3) ^ (row1 & 15)) << 3) | (hcol & 7))] = f2bf(v1);
    }
  }
  lgkm_bar();                           // Hs visible; V prefetch still in flight

  uint4 a20[8], a21[8];
#pragma unroll
  for (int s = 0; s < 8; ++s) {
    a20[s] = *(const uint4*)(Hs + l31 * 128 + (((s * 2 + khalf) ^ sx) << 3));
    a21[s] = *(const uint4*)(Hs + (32 + l31) * 128 + (((s * 2 + khalf) ^ sx) << 3));
  }

  u16* pp = (MODE == 0) ? part + (size_t)rank * SLAB : part;

  // ---- GEMM2 ----
#pragma unroll
  for (int dc = 0; dc < 8; ++dc) {
    const int cur = dc & 1;
    if (dc < 7) loadb(bb[cur ^ 1], Vf_e, dc + 1, wid, lane);
    f32x16 o0, o1;
#pragma unroll
    for (int i = 0; i < 16; ++i) { o0[i] = 0.f; o1[i] = 0.f; }
#pragma unroll
    for (int s = 0; s < 8; ++s) {
      o0 = mfma32(a20[s], bb[cur][s], o0);
      o1 = mfma32(a21[s], bb[cur][s], o1);
    }
    const int col = dc * 128 + wid * 32 + l31;
#pragma unroll
    for (int r = 0; r < 16; ++r) {
      const int row0 = (r & 3) + 8 * (r >> 2) + 4 * khalf;
      if (row0 < nrow) {
        const size_t p = (size_t)s_tok[row0] * DDIM + col;
        if (MODE <= 1)      pp[p] = f2bf(o0[r]);
        else if (MODE == 2) pp[p] = f2bf(bf2f(pp[p]) + o0[r]);
        else                out[p] = bf2f(pp[p]) + o0[r];
      }
      const int row1 = row0 + 32;
      if (row1 < nrow) {
        const size_t p = (size_t)s_tok[row1] * DDIM + col;
        if (MODE <= 1)      pp[p] = f2bf(o1[r]);
        else if (MODE == 2) pp[p] = f2bf(bf2f(pp[p]) + o1[r]);
        else                out[p] = bf2f(pp[p]) + o1[r];
      }
    }
  }
}

// ---------------- reduce: out = sum of 6 bf16 partial slabs ----------------
__global__ __launch_bounds__(256) void reduce_kernel(const u16* __restrict__ part,
                                                     float* __restrict__ out)
{
  const size_t i8 = ((size_t)blockIdx.x * 256 + threadIdx.x) * 8;
  float s[8];
#pragma unroll
  for (int j = 0; j < 8; ++j) s[j] = 0.f;
#pragma unroll
  for (int r = 0; r < 6; ++r) {
    const uint4 v = *(const uint4*)(part + r * SLAB + i8);
    const unsigned w[4] = {v.x, v.y, v.z, v.w};
#pragma unroll
    for (int q = 0; q < 4; ++q) {
      s[q*2+0] += __uint_as_float((w[q] & 0xffffu) << 16);
      s[q*2+1] += __uint_as_float(w[q] & 0xffff0000u);
    }
  }
  float4 o0 = make_float4(s[0], s[1], s[2], s[3]);
  float4 o1 = make_float4(s[4], s[5], s[6], s[7]);
  *(float4*)(out + i8) = o0;
  *(float4*)(out + i8 + 4) = o1;
}

extern "C" void kernel_launch(void* const* d_in, const int* in_sizes, int n_in,
                              void* d_out, int out_size, void* d_ws, size_t ws_size,
                              hipStream_t stream)
{
  const float* X    = (const float*)d_in[0];
  const float* SI   = (const float*)d_in[1];
  const float* keys = (const float*)d_in[2];
  const float* vals = (const float*)d_in[3];
  const float* ES   = (const float*)d_in[4];
  const float* bias = (const float*)d_in[5];
  float* out = (float*)d_out;
  float* out_sel = out + SLAB;

  char* ws = (char*)d_ws;
  int*   counts   = (int*)(ws + 0);
  int*   cursor   = (int*)(ws + 512);
  int*   offsets  = (int*)(ws + 1024);
  int4*  jm       = (int4*)(ws + 2048);          // 8192 entries (fused + serial)
  int*   list_tok = (int*)(ws + 133120);
  float* list_w   = (float*)(ws + 526336);
  float* w6       = (float*)(ws + 919552);
  int*   sel_e    = (int*)(ws + 1312768);
  u16*   Xb       = (u16*)(ws + 1576960);        // 32MB
  u16*   Kf       = (u16*)(ws + 35131392);       // 8MB
  u16*   Vf       = (u16*)(ws + 43520000);       // 8MB
  u16*   part     = (u16*)(ws + 51908608);       // fused: 6x32MB; serial: 32MB acc

  const bool fused = ws_size >= (size_t)51908608 + 6 * SLAB * 2;

  hipMemsetAsync(counts, 0, 1024, stream);

  cvt_x_kernel<<<(NTOK * DDIM) / (256 * 16), 256, 0, stream>>>(X, Xb);
  prep_k_kernel<<<dim3(8, NEXP), 256, 0, stream>>>(keys, Kf);
  prep_v_kernel<<<dim3(8, NEXP), 256, 0, stream>>>(vals, Vf);

  router_kernel<<<NTOK / 16, 256, 0, stream>>>(SI, ES, bias, out_sel, w6, sel_e, counts);
  scan_kernel<<<1, 256, 0, stream>>>(counts, offsets, jm);
  scatter_kernel<<<NTOK / 256, 256, 0, stream>>>(sel_e, w6, offsets, cursor, list_tok, list_w);

  if (fused) {
    ffn_pass<0><<<NJOBS_F, 256, 0, stream>>>(Xb, Kf, Vf, jm, CPX_F,
                                             list_tok, list_w, part, out);
    reduce_kernel<<<SLAB / (256 * 8), 256, 0, stream>>>(part, out);
  } else {
    // serial fallback: shared-30 write, shared-31 + ranks 0..2 rmw, rank 3 final
    const int sec[6]  = {4, 5, 0, 1, 2, 3};
    const int mode[6] = {1, 2, 2, 2, 2, 3};
    for (int i = 0; i < 6; ++i) {
      const int4* jms = jm + 2048 + sec[i] * NJOBS_S;
      if (mode[i] == 1)
        ffn_pass<1><<<NJOBS_S, 256, 0, stream>>>(Xb, Kf, Vf, jms, CPX_S,
                                                 list_tok, list_w, part, out);
      else if (mode[i] == 2)
        ffn_pass<2><<<NJOBS_S, 256, 0, stream>>>(Xb, Kf, Vf, jms, CPX_S,
                                                 list_tok, list_w, part, out);
      else
        ffn_pass<3><<<NJOBS_S, 256, 0, stream>>>(Xb, Kf, Vf, jms, CPX_S,
                                                 list_tok, list_w, part, out);
    }
  }
}